// Round 14
// baseline (3681.443 us; speedup 1.0000x reference)
//
#include <hip/hip_runtime.h>
#include <stdint.h>

#define T_STEPS 320
#define BATCH   192
#define HID     1024
#define NBLK    256

typedef unsigned short u16;
typedef __bf16 bf16x8 __attribute__((ext_vector_type(8)));
typedef float  f32x4  __attribute__((ext_vector_type(4)));
typedef unsigned int u32x4 __attribute__((ext_vector_type(4)));

// ---------------- workspace layout (bytes) ----------------
#define OFF_BAR      0u          // [4 grp][64 flags] u32 @64B stride = 16384
#define OFF_PART     16384u      // [2 dir][4][192][320] f32 partial logits = 1966080
#define MEMSET_BYTES 1982464u
#define OFF_C0       1982464u    // [2][192][1024] f32 = 1572864
#define OFF_H        3555328u    // [2 dir][2 buf][192][1024] bf16 (fallback path)
#define OFF_WPACK    5128192u    // packed W_hh bf16 fragments = 16777216
#define OFF_COEF     21905408u   // [2][64][64] float4 = 131072
#define WS_NEED      22036480u
// ring path: per-step h panels, [2 dir][P][192][1024] bf16, P from ws_size
#define OFF_HT       22036480u
#define PANEL_ELEMS  196608u                    // 192*1024 u16
#define P_COST       786432u                    // both dirs per ring slot

// LDS: W slice 131072 B + DMP [4 wk][24 row][68] f32 = 26112 B + flag
#define DMP_OFF_B    131072
#define DMP_WK_STRIDE 1632       // floats (24*68)
#define DYN_LDS      157200

__device__ __forceinline__ u16 f2bf(float f) {
  unsigned u = __float_as_uint(f);
  unsigned r = (u + 0x7FFFu + ((u >> 16) & 1u)) >> 16;
  return (u16)r;
}
__device__ __forceinline__ float sigm(float x)   { return 1.f / (1.f + __expf(-x)); }
__device__ __forceinline__ float tanh_f(float x) { return 1.f - 2.f / (1.f + __expf(2.f * x)); }

// ---------------- prep: pack W_hh into MFMA-fragment order (bf16) ----------------
__global__ void pack_k(const float* __restrict__ Whhf, const float* __restrict__ Whhb,
                       u16* __restrict__ wpack)
{
  int lin = blockIdx.x * 256 + threadIdx.x;      // < 1048576
  int lane = lin & 63;
  int cg   = (lin >> 6) & 3;
  int ks   = (lin >> 8) & 31;
  int jsl  = (lin >> 13) & 63;
  int dir  = (lin >> 19) & 1;
  int col  = cg * 16 + (lane & 15);
  int R    = (col & 3) * 1024 + jsl * 16 + (col >> 2);
  int kb   = ks * 32 + (lane >> 4) * 8;
  const float* W = dir ? Whhb : Whhf;
  const float* src = W + (size_t)R * 1024 + kb;
  unsigned w[4];
  #pragma unroll
  for (int e = 0; e < 4; ++e) {
    unsigned lo = f2bf(src[2 * e]);
    unsigned hi = f2bf(src[2 * e + 1]);
    w[e] = lo | (hi << 16);
  }
  *((uint4*)(wpack + (size_t)lin * 8)) = make_uint4(w[0], w[1], w[2], w[3]);
}

// ---------------- prep: per-gate-row x-projection coefficients ----------------
__global__ void coef_k(const float* __restrict__ Wihf, const float* __restrict__ bihf,
                       const float* __restrict__ bhhf,
                       const float* __restrict__ Wihb, const float* __restrict__ bihb,
                       const float* __restrict__ bhhb, float* __restrict__ coef)
{
  int id  = blockIdx.x * 256 + threadIdx.x;      // < 8192
  int col = id & 63;
  int jsl = (id >> 6) & 63;
  int dir = (id >> 12) & 1;
  int R   = (col & 3) * 1024 + jsl * 16 + (col >> 2);
  const float* Wih = dir ? Wihb : Wihf;
  const float* bi  = dir ? bihb : bihf;
  const float* bh  = dir ? bhhb : bhhf;
  float4 v;
  v.x = Wih[(size_t)R * 2 + 0];
  v.y = Wih[(size_t)R * 2 + 1];
  v.z = bi[R] + bh[R];
  v.w = 0.f;
  ((float4*)coef)[id] = v;
}

// ---------------- prep: h0/c0 projections ----------------
__global__ void init_k(const float* __restrict__ ctrl, const float* __restrict__ ratw,
                       const float* __restrict__ Whf, const float* __restrict__ bhf,
                       const float* __restrict__ Whb, const float* __restrict__ bhb,
                       const float* __restrict__ Wcf, const float* __restrict__ bcf,
                       const float* __restrict__ Wcb, const float* __restrict__ bcb,
                       u16* hb, float* c0, size_t hstride)
{
  int idx = blockIdx.x * 256 + threadIdx.x;      // 0..196607
  int m = blockIdx.y;                             // 0 h0f, 1 h0b, 2 c0f, 3 c0b
  int b = idx >> 10;
  int h = idx & 1023;
  const float* W  = (m == 0) ? Whf : (m == 1) ? Whb : (m == 2) ? Wcf : Wcb;
  const float* bi = (m == 0) ? bhf : (m == 1) ? bhb : (m == 2) ? bcf : bcb;
  float acc = bi[h];
  const float* wr = W + h * 24;
  #pragma unroll
  for (int k = 0; k < 16; ++k) acc += wr[k] * ctrl[b * 16 + k];
  #pragma unroll
  for (int k = 0; k < 8; ++k)  acc += wr[16 + k] * ratw[b * 8 + k];
  acc = tanh_f(acc);
  if (m < 2) hb[(size_t)m * hstride + (size_t)b * HID + h] = f2bf(acc);
  else       c0[((size_t)(m - 2) * BATCH + b) * HID + h] = acc;
}

// ---------------- persistent bi-LSTM ----------------
// 256 blocks x 512 threads, 1/CU. block = (dir, bhalf, jsl).
// CACHED=1 (ring path): h(t) written round-robin into a P-panel ring with sc0sc1
//   write-through to L3; consumers use PLAIN CACHED loads -> per-XCD L2 MSHR-
//   dedupes the 64-block convoy (6.1 -> ~0.8 MB/XCD/step on the ~550GB/s
//   XCD-fabric link that R5-R10 saturated). Address-reuse staleness killed
//   architecturally: each block runs `buffer_inv` (L1+L2 inv, mechanism
//   validated end-to-end by R11's passing run) every IV = P-2 steps, strictly
//   inside any line's P-step reuse window; no loads touch a panel between its
//   inv and its next write-through -> no stale refill possible.
// CACHED=0: exact R10 fallback (2-buffer ring, sc0sc1 bypass loads).
// W slice in LDS (B = ds_read, zero vmcnt); all 24 A loads issued at step start.
// Sync: store/poll flag barrier (no RMWs); logit atomics after the flag store.

#define ALD_B(S, OB) \
  asm volatile("global_load_dwordx4 %0, %1, off offset:" #OB " sc0 sc1" : "=v"(aq[S][0]) : "v"(ab0)); \
  asm volatile("global_load_dwordx4 %0, %1, off offset:" #OB " sc0 sc1" : "=v"(aq[S][1]) : "v"(ab1)); \
  asm volatile("global_load_dwordx4 %0, %1, off offset:" #OB " sc0 sc1" : "=v"(aq[S][2]) : "v"(ab2));

#define ALD_C(S, OB) \
  asm volatile("global_load_dwordx4 %0, %1, off offset:" #OB : "=v"(aq[S][0]) : "v"(ab0)); \
  asm volatile("global_load_dwordx4 %0, %1, off offset:" #OB : "=v"(aq[S][1]) : "v"(ab1)); \
  asm volatile("global_load_dwordx4 %0, %1, off offset:" #OB : "=v"(aq[S][2]) : "v"(ab2));

#define BLDS(P_, C) { \
  bv[P_][0] = *(const bf16x8*)(bWl + (C) * 2048 + 0);   \
  bv[P_][1] = *(const bf16x8*)(bWl + (C) * 2048 + 512); \
  bv[P_][2] = *(const bf16x8*)(bWl + (C) * 2048 + 1024);\
  bv[P_][3] = *(const bf16x8*)(bWl + (C) * 2048 + 1536); }

#define WB(n) \
  asm volatile("s_waitcnt vmcnt(" #n ")" ::: "memory"); \
  __builtin_amdgcn_sched_barrier(0);

#define MM(C, P_) { \
  _Pragma("unroll") \
  for (int mt_ = 0; mt_ < 3; ++mt_) { \
    bf16x8 a_ = __builtin_bit_cast(bf16x8, aq[C][mt_]); \
    _Pragma("unroll") \
    for (int n_ = 0; n_ < 4; ++n_) { \
      acc[mt_][n_] = __builtin_amdgcn_mfma_f32_16x16x32_bf16(a_, bv[P_][n_], acc[mt_][n_], 0, 0, 0); \
    } \
  } }

#define HST(PT, VL) asm volatile("global_store_short %0, %1, off sc0 sc1" :: "v"(PT), "v"(VL) : "memory")

template<int CACHED>
__launch_bounds__(512, 1)
__global__ void lstm_persist(const float* __restrict__ x,
                             const float* __restrict__ wlog,
                             float* part,
                             const float* __restrict__ c0,
                             u16* hb,
                             const u16* __restrict__ wpack,
                             const float* __restrict__ coef,
                             unsigned* bar,
                             int PN, int IV)
{
  extern __shared__ char lds[];
  u16*   Wlds = (u16*)lds;                          // [32 ks][4 cg][64 lane][8]
  float* DMP  = (float*)(lds + DMP_OFF_B);          // [4 wk][24][68] f32
  int*   ldsflag = (int*)(lds + DMP_OFF_B + 26112);

  const int tid   = threadIdx.x;
  const int bid   = blockIdx.x;
  const int dir   = bid >> 7;
  const int bhalf = (bid >> 6) & 1;
  const int jsl   = bid & 63;
  const int wave  = tid >> 6;
  const int lane  = tid & 63;
  const int wm    = wave >> 2;                      // row half (48 rows)
  const int wk    = wave & 3;                       // K quarter (256)
  const int grp   = dir * 2 + bhalf;                // sync group (64 blocks)
  const int q4    = (lane >> 4) * 4;
  const int cl    = lane & 15;

  if (tid == 0) *ldsflag = 0;

  { // W slice -> LDS once (normal cached path)
    const uint4* wsrc = (const uint4*)wpack + (size_t)(dir * 64 + jsl) * 8192;
    uint4* wdst = (uint4*)Wlds;
    #pragma unroll
    for (int i = 0; i < 16; ++i) wdst[tid + i * 512] = wsrc[tid + i * 512];
  }

  // ---- pointwise ownership: waves 0..5 (tid<384): row r = p*24 + (tid>>4), j = tid&15 ----
  const int j    = tid & 15;
  const int rloc = tid >> 4;                        // 0..23 valid when tid<384
  const bool pw  = (tid < 384);
  const int jglob = jsl * 16 + j;
  float4 cf0, cf1, cf2, cf3;
  {
    const float4* cp = (const float4*)coef + ((dir * 64 + jsl) * 64 + j * 4);
    cf0 = cp[0]; cf1 = cp[1]; cf2 = cp[2]; cf3 = cp[3];
  }
  const float wlg = wlog[dir * 1024 + jglob];

  float creg[4];
  int   bgm[4];
  #pragma unroll
  for (int p = 0; p < 4; ++p) {
    int bg = bhalf * 96 + p * 24 + rloc;
    bgm[p]  = bg;
    creg[p] = pw ? c0[((size_t)dir * BATCH + bg) * HID + jglob] : 0.f;
  }

  // ---- GEMM-side addressing ----
  const int arow0 = bhalf * 96 + wm * 48 + 0 * 16 + cl;
  const int arow1 = arow0 + 16;
  const int arow2 = arow0 + 32;
  const int koff  = wk * 256 + (lane >> 4) * 8;                    // u16 units
  const u16* bWl  = Wlds + (size_t)wk * 16384 + lane * 8;          // LDS W stream

  float* pbase = part + ((size_t)(dir * 4 + (jsl & 3)) * BATCH) * T_STEPS;

  // flag barrier pointers: group base, own flag (jsl), poll target (lane)
  unsigned* gflags = bar + grp * 1024;              // 64 flags @ 16 u32 stride
  unsigned* myflag = gflags + jsl * 16;
  const unsigned* pollp = gflags + lane * 16;

  float lpv[4];
  int   lpo[4];

  int sp   = 0;      // ring source panel
  int invc = 0;      // inv countdown (CACHED only)

  __syncthreads();

  for (int s = 0; s < T_STEPS; ++s) {
    // ---- periodic L1+L2 invalidate (ring path) ----
    if constexpr (CACHED) {
      if (invc == 0) {
        if (wave == 0) {
          asm volatile("buffer_inv sc0 sc1" ::: "memory");
          asm volatile("s_waitcnt vmcnt(0)" ::: "memory");
        }
        __syncthreads();
      }
      if (++invc >= IV) invc = 0;
    }

    int dp = sp + 1; if (dp == PN) dp = 0;
    const u16* hsrc = hb + ((size_t)(dir * PN + sp)) * PANEL_ELEMS;
    u16*       hdst = hb + ((size_t)(dir * PN + dp)) * PANEL_ELEMS;
    sp = dp;
    const u16* ab0 = hsrc + (size_t)arow0 * HID + koff;
    const u16* ab1 = hsrc + (size_t)arow1 * HID + koff;
    const u16* ab2 = hsrc + (size_t)arow2 * HID + koff;

    f32x4 acc[3][4];
    #pragma unroll
    for (int mt = 0; mt < 3; ++mt)
      #pragma unroll
      for (int n = 0; n < 4; ++n)
        acc[mt][n] = (f32x4){0.f, 0.f, 0.f, 0.f};

    u32x4  aq[8][3];
    bf16x8 bv[2][4];

    // issue ALL 8 K-chunks of A up front (24 loads, one RTT exposure)
    if constexpr (CACHED) {
      ALD_C(0, 0)   ALD_C(1, 64)  ALD_C(2, 128) ALD_C(3, 192)
      ALD_C(4, 256) ALD_C(5, 320) ALD_C(6, 384) ALD_C(7, 448)
    } else {
      ALD_B(0, 0)   ALD_B(1, 64)  ALD_B(2, 128) ALD_B(3, 192)
      ALD_B(4, 256) ALD_B(5, 320) ALD_B(6, 384) ALD_B(7, 448)
    }

    BLDS(0, 0)
    BLDS(1, 1) WB(21) MM(0, 0)
    BLDS(0, 2) WB(18) MM(1, 1)
    BLDS(1, 3) WB(15) MM(2, 0)
    BLDS(0, 4) WB(12) MM(3, 1)
    BLDS(1, 5) WB(9)  MM(4, 0)
    BLDS(0, 6) WB(6)  MM(5, 1)
    BLDS(1, 7) WB(3)  MM(6, 0)
               WB(0)  MM(7, 1)

    const int t_x = dir ? (T_STEPS - 1 - s) : s;

    // ---- 4 quarter-row phases: masked dump -> sync -> gather+pointwise -> sync ----
    #pragma unroll
    for (int p = 0; p < 4; ++p) {
      if (wm == (p >> 1)) {
        const int plo = (p & 1) * 24;
        float* dst = DMP + wk * DMP_WK_STRIDE;
        #pragma unroll
        for (int mt = 0; mt < 3; ++mt)
          #pragma unroll
          for (int n = 0; n < 4; ++n)
            #pragma unroll
            for (int r = 0; r < 4; ++r) {
              int row = mt * 16 + q4 + r;
              if (row >= plo && row < plo + 24)
                dst[(row - plo) * 68 + n * 16 + cl] = acc[mt][n][r];
            }
      }
      __syncthreads();

      if (pw) {
        const int ga = rloc * 68 + (j >> 2) * 16 + (j & 3) * 4;
        f32x4 p0 = *(const f32x4*)(DMP + 0 * DMP_WK_STRIDE + ga);
        f32x4 p1 = *(const f32x4*)(DMP + 1 * DMP_WK_STRIDE + ga);
        f32x4 p2 = *(const f32x4*)(DMP + 2 * DMP_WK_STRIDE + ga);
        f32x4 p3 = *(const f32x4*)(DMP + 3 * DMP_WK_STRIDE + ga);
        f32x4 g4 = (p0 + p1) + (p2 + p3);          // (i,f,g,o)
        int bg = bgm[p];
        float2 xv = *(const float2*)(x + ((size_t)t_x * BATCH + bg) * 2);
        float pi = g4[0] + cf0.x * xv.x + cf0.y * xv.y + cf0.z;
        float pf = g4[1] + cf1.x * xv.x + cf1.y * xv.y + cf1.z;
        float pg = g4[2] + cf2.x * xv.x + cf2.y * xv.y + cf2.z;
        float po = g4[3] + cf3.x * xv.x + cf3.y * xv.y + cf3.z;
        float ig = sigm(pi), fg = sigm(pf), gv = tanh_f(pg), og = sigm(po);
        float c = fg * creg[p] + ig * gv;
        creg[p] = c;
        float h = og * tanh_f(c);
        u16* hp = hdst + (size_t)bg * HID + jglob;
        unsigned hv = (unsigned)f2bf(h);
        HST(hp, hv);
        float lp = h * wlg;
        lp += __shfl_xor(lp, 1);
        lp += __shfl_xor(lp, 2);
        lp += __shfl_xor(lp, 4);
        lp += __shfl_xor(lp, 8);
        lpv[p] = lp;
        lpo[p] = bg * T_STEPS + t_x;
      }
      __syncthreads();
    }

    // ---- drain own h stores (per-wave), then block-wide sync => all drained ----
    asm volatile("s_waitcnt vmcnt(0)" ::: "memory");
    __syncthreads();

    // ---- store/poll flag barrier (no RMWs); logit atomics AFTER the flag ----
    if (tid == 0) {
      unsigned nv = (unsigned)(s + 1);
      asm volatile("global_store_dword %0, %1, off sc0 sc1" :: "v"(myflag), "v"(nv) : "memory");
    }
    if (pw && j == 0) {
      atomicAdd(&pbase[lpo[0]], lpv[0]);
      atomicAdd(&pbase[lpo[1]], lpv[1]);
      atomicAdd(&pbase[lpo[2]], lpv[2]);
      atomicAdd(&pbase[lpo[3]], lpv[3]);
    }
    if (wave == 0) {
      const unsigned tgt = (unsigned)(s + 1);
      long guard = 0;
      for (;;) {
        unsigned fv;
        asm volatile("global_load_dword %0, %1, off sc0 sc1" : "=v"(fv) : "v"(pollp));
        asm volatile("s_waitcnt vmcnt(0)" ::: "memory");
        if (__all(fv >= tgt)) break;
        if (++guard > (1L << 20)) { if (lane == 0) *ldsflag = 1; break; }
        __builtin_amdgcn_s_sleep(1);
      }
    }
    __syncthreads();
    if (*ldsflag) return;   // sync failure: bail instead of hanging
  }
}

// ---------------- post: sum partials -> softmax -> cumsum -> Bezier -> curves + reg ----------------
__global__ void post_k(const float* __restrict__ part, const float* __restrict__ ctrl,
                       const float* __restrict__ ratw, float* __restrict__ out)
{
  __shared__ float sh[T_STEPS + 64];
  const int b = blockIdx.x;
  const int t = threadIdx.x;          // 320 threads
  float l = 0.f;
  #pragma unroll
  for (int p = 0; p < 8; ++p)
    l += part[((size_t)p * BATCH + b) * T_STEPS + t];
  sh[t] = l;
  __syncthreads();
  if (t < 64) {
    float mm = sh[t];
    for (int i = t + 64; i < T_STEPS; i += 64) mm = fmaxf(mm, sh[i]);
    #pragma unroll
    for (int o = 32; o; o >>= 1) mm = fmaxf(mm, __shfl_xor(mm, o));
    if (t == 0) sh[T_STEPS] = mm;
  }
  __syncthreads();
  const float m = sh[T_STEPS];
  float e = __expf(l - m);
  __syncthreads();
  sh[t] = e;
  __syncthreads();
  for (int off = 1; off < T_STEPS; off <<= 1) {
    float v = (t >= off) ? sh[t - off] : 0.f;
    __syncthreads();
    sh[t] += v;
    __syncthreads();
  }
  const float total = sh[T_STEPS - 1];
  const float ts = sh[t] / total;

  float px[8], py[8], rr[8];
  #pragma unroll
  for (int n = 0; n < 8; ++n) {
    px[n] = ctrl[b * 16 + 2 * n];
    py[n] = ctrl[b * 16 + 2 * n + 1];
    rr[n] = ratw[b * 8 + n];
  }
  const float C[8] = {1.f, 7.f, 21.f, 35.f, 35.f, 21.f, 7.f, 1.f};
  float tp[8], up[8];
  tp[0] = 1.f; up[0] = 1.f;
  const float u = 1.f - ts;
  #pragma unroll
  for (int n = 1; n < 8; ++n) { tp[n] = tp[n - 1] * ts; up[n] = up[n - 1] * u; }
  float den = 0.f, nx = 0.f, ny = 0.f;
  #pragma unroll
  for (int n = 0; n < 8; ++n) {
    float w = C[n] * tp[n] * up[7 - n] * rr[n];
    den += w; nx += w * px[n]; ny += w * py[n];
  }
  out[(b * T_STEPS + t) * 2 + 0] = nx / den;
  out[(b * T_STEPS + t) * 2 + 1] = ny / den;

  if (b == 0) {   // regularizer scalar
    __syncthreads();
    if (t < BATCH) {
      float s2 = 0.f;
      #pragma unroll
      for (int n = 0; n < 7; ++n) {
        float dx = ctrl[t * 16 + 2 * n + 2] - ctrl[t * 16 + 2 * n + 0];
        float dy = ctrl[t * 16 + 2 * n + 3] - ctrl[t * 16 + 2 * n + 1];
        s2 += dx * dx + dy * dy;
      }
      sh[t] = s2;
    }
    __syncthreads();
    if (t == 0) {
      float tot = 0.f;
      for (int i = 0; i < BATCH; ++i) tot += sh[i];
      out[BATCH * T_STEPS * 2] = tot / (float)(BATCH * 7);
    }
  }
}

extern "C" void kernel_launch(void* const* d_in, const int* in_sizes, int n_in,
                              void* d_out, int out_size, void* d_ws, size_t ws_size,
                              hipStream_t stream)
{
  const float* x    = (const float*)d_in[0];
  const float* ctrl = (const float*)d_in[1];
  const float* ratw = (const float*)d_in[2];
  const float* Whf  = (const float*)d_in[3];
  const float* bhf  = (const float*)d_in[4];
  const float* Whb  = (const float*)d_in[5];
  const float* bhb  = (const float*)d_in[6];
  const float* Wcf  = (const float*)d_in[7];
  const float* bcf  = (const float*)d_in[8];
  const float* Wcb  = (const float*)d_in[9];
  const float* bcb  = (const float*)d_in[10];
  const float* Wihf = (const float*)d_in[11];
  const float* Whhf = (const float*)d_in[12];
  const float* bihf = (const float*)d_in[13];
  const float* bhhf = (const float*)d_in[14];
  const float* Wihb = (const float*)d_in[15];
  const float* Whhb = (const float*)d_in[16];
  const float* bihb = (const float*)d_in[17];
  const float* bhhb = (const float*)d_in[18];
  const float* Wlog = (const float*)d_in[19];
  float* out = (float*)d_out;
  char*  ws  = (char*)d_ws;
  if (ws_size < (size_t)WS_NEED) return;

  // ring sizing from available workspace
  size_t availB = (ws_size > (size_t)OFF_HT) ? (ws_size - (size_t)OFF_HT) : 0;
  long Pl = (long)(availB / (size_t)P_COST);
  int P = (int)(Pl > 322 ? 322 : Pl);
  const bool cached = (P >= 4);

  unsigned* bar    = (unsigned*)(ws + OFF_BAR);
  float*    part   = (float*)(ws + OFF_PART);
  float*    c0     = (float*)(ws + OFF_C0);
  u16*      hsmall = (u16*)(ws + OFF_H);
  u16*      hring  = (u16*)(ws + OFF_HT);
  u16*      wpack  = (u16*)(ws + OFF_WPACK);
  float*    coef   = (float*)(ws + OFF_COEF);

  u16*   hb      = cached ? hring : hsmall;
  int    PN      = cached ? P : 2;
  int    IV      = (cached && P < 322) ? (P - 2) : (1 << 30);
  size_t hstride = (size_t)PN * PANEL_ELEMS;

  hipMemsetAsync(ws, 0, MEMSET_BYTES, stream);   // flags + partial logits
  pack_k<<<4096, 256, 0, stream>>>(Whhf, Whhb, wpack);
  coef_k<<<32, 256, 0, stream>>>(Wihf, bihf, bhhf, Wihb, bihb, bhhb, coef);
  init_k<<<dim3(768, 4), 256, 0, stream>>>(ctrl, ratw, Whf, bhf, Whb, bhb,
                                           Wcf, bcf, Wcb, bcb, hb, c0, hstride);
  if (cached) {
    hipFuncSetAttribute((const void*)lstm_persist<1>,
                        hipFuncAttributeMaxDynamicSharedMemorySize, DYN_LDS);
    lstm_persist<1><<<NBLK, 512, DYN_LDS, stream>>>(x, Wlog, part, c0, hb, wpack, coef, bar, PN, IV);
  } else {
    hipFuncSetAttribute((const void*)lstm_persist<0>,
                        hipFuncAttributeMaxDynamicSharedMemorySize, DYN_LDS);
    lstm_persist<0><<<NBLK, 512, DYN_LDS, stream>>>(x, Wlog, part, c0, hb, wpack, coef, bar, PN, IV);
  }
  post_k<<<BATCH, T_STEPS, 0, stream>>>(part, ctrl, ratw, out);
}

// Round 15
// 3661.226 us; speedup vs baseline: 1.0055x; 1.0055x over previous
//
#include <hip/hip_runtime.h>
#include <stdint.h>

#define T_STEPS 320
#define BATCH   192
#define HID     1024
#define NBLK    256

typedef unsigned short u16;
typedef __bf16 bf16x8 __attribute__((ext_vector_type(8)));
typedef float  f32x4  __attribute__((ext_vector_type(4)));
typedef unsigned int u32x4 __attribute__((ext_vector_type(4)));

// ---------------- workspace layout (bytes) ----------------
#define OFF_BAR      0u          // [4 grp][64 flags] u32 @64B stride = 16384
#define OFF_PART     16384u      // [2 dir][4][192][320] f32 partial logits = 1966080
#define MEMSET_BYTES 1982464u
#define OFF_C0       1982464u    // [2][192][1024] f32 = 1572864
#define OFF_H        3555328u    // [2 dir][2 buf][192][1024] bf16 (fallback path)
#define OFF_COEF     5128192u    // [2][64][64] float4 = 131072
#define WS_NEED      5259264u
// ring path: per-step h panels, [2 dir][P][192][1024] bf16, P from ws_size
#define OFF_HT       5259264u
#define PANEL_ELEMS  196608u                    // 192*1024 u16
#define P_COST       786432u                    // both dirs per ring slot

// LDS: W slice 131072 B + DMP [4 wk][24 row][68] f32 = 26112 B + flag
#define DMP_OFF_B    131072
#define DMP_WK_STRIDE 1632       // floats (24*68)
#define DYN_LDS      157200

__device__ __forceinline__ u16 f2bf(float f) {
  unsigned u = __float_as_uint(f);
  unsigned r = (u + 0x7FFFu + ((u >> 16) & 1u)) >> 16;
  return (u16)r;
}
__device__ __forceinline__ float sigm(float x)   { return 1.f / (1.f + __expf(-x)); }
__device__ __forceinline__ float tanh_f(float x) { return 1.f - 2.f / (1.f + __expf(2.f * x)); }

// ---------------- prep: per-gate-row x-projection coefficients ----------------
__global__ void coef_k(const float* __restrict__ Wihf, const float* __restrict__ bihf,
                       const float* __restrict__ bhhf,
                       const float* __restrict__ Wihb, const float* __restrict__ bihb,
                       const float* __restrict__ bhhb, float* __restrict__ coef)
{
  int id  = blockIdx.x * 256 + threadIdx.x;      // < 8192
  int col = id & 63;
  int jsl = (id >> 6) & 63;
  int dir = (id >> 12) & 1;
  int R   = (col & 3) * 1024 + jsl * 16 + (col >> 2);
  const float* Wih = dir ? Wihb : Wihf;
  const float* bi  = dir ? bihb : bihf;
  const float* bh  = dir ? bhhb : bhhf;
  float4 v;
  v.x = Wih[(size_t)R * 2 + 0];
  v.y = Wih[(size_t)R * 2 + 1];
  v.z = bi[R] + bh[R];
  v.w = 0.f;
  ((float4*)coef)[id] = v;
}

// ---------------- prep: h0/c0 projections ----------------
__global__ void init_k(const float* __restrict__ ctrl, const float* __restrict__ ratw,
                       const float* __restrict__ Whf, const float* __restrict__ bhf,
                       const float* __restrict__ Whb, const float* __restrict__ bhb,
                       const float* __restrict__ Wcf, const float* __restrict__ bcf,
                       const float* __restrict__ Wcb, const float* __restrict__ bcb,
                       u16* hb, float* c0, size_t hstride)
{
  int idx = blockIdx.x * 256 + threadIdx.x;      // 0..196607
  int m = blockIdx.y;                             // 0 h0f, 1 h0b, 2 c0f, 3 c0b
  int b = idx >> 10;
  int h = idx & 1023;
  const float* W  = (m == 0) ? Whf : (m == 1) ? Whb : (m == 2) ? Wcf : Wcb;
  const float* bi = (m == 0) ? bhf : (m == 1) ? bhb : (m == 2) ? bcf : bcb;
  float acc = bi[h];
  const float* wr = W + h * 24;
  #pragma unroll
  for (int k = 0; k < 16; ++k) acc += wr[k] * ctrl[b * 16 + k];
  #pragma unroll
  for (int k = 0; k < 8; ++k)  acc += wr[16 + k] * ratw[b * 8 + k];
  acc = tanh_f(acc);
  if (m < 2) hb[(size_t)m * hstride + (size_t)b * HID + h] = f2bf(acc);
  else       c0[((size_t)(m - 2) * BATCH + b) * HID + h] = acc;
}

// ---------------- persistent bi-LSTM ----------------
// 256 blocks x 512 threads, 1/CU. block = (dir, bhalf, jsl).
// W_hh slice packed f32->bf16 IN-KERNEL (prologue) straight into LDS -- no wpack
// buffer, freeing 16.7 MB of workspace for the h ring (P ~= 25 at 24 MiB ws).
// CACHED=1 (ring path): h(t) written round-robin into a P-panel ring with sc0sc1
//   write-through to L3; consumers use PLAIN CACHED loads -> per-XCD L2 MSHR-
//   dedupes the 64-block convoy (6.1 -> ~0.8 MB/XCD/step on the ~550GB/s
//   XCD-fabric link that R5-R10 saturated). Address-reuse staleness killed
//   architecturally: each block runs `buffer_inv` (L1+L2 inv; mechanism
//   validated end-to-end by R11's passing run) every IV = P-2 steps, strictly
//   inside any line's P-step reuse window -> no stale refill possible.
// CACHED=0: exact R10 fallback (2-buffer ring, sc0sc1 bypass loads).
// Sync: store/poll flag barrier (no RMWs); logit atomics after the flag store.

#define ALD_B(S, OB) \
  asm volatile("global_load_dwordx4 %0, %1, off offset:" #OB " sc0 sc1" : "=v"(aq[S][0]) : "v"(ab0)); \
  asm volatile("global_load_dwordx4 %0, %1, off offset:" #OB " sc0 sc1" : "=v"(aq[S][1]) : "v"(ab1)); \
  asm volatile("global_load_dwordx4 %0, %1, off offset:" #OB " sc0 sc1" : "=v"(aq[S][2]) : "v"(ab2));

#define ALD_C(S, OB) \
  asm volatile("global_load_dwordx4 %0, %1, off offset:" #OB : "=v"(aq[S][0]) : "v"(ab0)); \
  asm volatile("global_load_dwordx4 %0, %1, off offset:" #OB : "=v"(aq[S][1]) : "v"(ab1)); \
  asm volatile("global_load_dwordx4 %0, %1, off offset:" #OB : "=v"(aq[S][2]) : "v"(ab2));

#define BLDS(P_, C) { \
  bv[P_][0] = *(const bf16x8*)(bWl + (C) * 2048 + 0);   \
  bv[P_][1] = *(const bf16x8*)(bWl + (C) * 2048 + 512); \
  bv[P_][2] = *(const bf16x8*)(bWl + (C) * 2048 + 1024);\
  bv[P_][3] = *(const bf16x8*)(bWl + (C) * 2048 + 1536); }

#define WB(n) \
  asm volatile("s_waitcnt vmcnt(" #n ")" ::: "memory"); \
  __builtin_amdgcn_sched_barrier(0);

#define MM(C, P_) { \
  _Pragma("unroll") \
  for (int mt_ = 0; mt_ < 3; ++mt_) { \
    bf16x8 a_ = __builtin_bit_cast(bf16x8, aq[C][mt_]); \
    _Pragma("unroll") \
    for (int n_ = 0; n_ < 4; ++n_) { \
      acc[mt_][n_] = __builtin_amdgcn_mfma_f32_16x16x32_bf16(a_, bv[P_][n_], acc[mt_][n_], 0, 0, 0); \
    } \
  } }

#define HST(PT, VL) asm volatile("global_store_short %0, %1, off sc0 sc1" :: "v"(PT), "v"(VL) : "memory")

template<int CACHED>
__launch_bounds__(512, 1)
__global__ void lstm_persist(const float* __restrict__ x,
                             const float* __restrict__ wlog,
                             float* part,
                             const float* __restrict__ c0,
                             u16* hb,
                             const float* __restrict__ Whhf,
                             const float* __restrict__ Whhb,
                             const float* __restrict__ coef,
                             unsigned* bar,
                             int PN, int IV)
{
  extern __shared__ char lds[];
  u16*   Wlds = (u16*)lds;                          // [32 ks][4 cg][64 lane][8]
  float* DMP  = (float*)(lds + DMP_OFF_B);          // [4 wk][24][68] f32
  int*   ldsflag = (int*)(lds + DMP_OFF_B + 26112);

  const int tid   = threadIdx.x;
  const int bid   = blockIdx.x;
  const int dir   = bid >> 7;
  const int bhalf = (bid >> 6) & 1;
  const int jsl   = bid & 63;
  const int wave  = tid >> 6;
  const int lane  = tid & 63;
  const int wm    = wave >> 2;                      // row half (48 rows)
  const int wk    = wave & 3;                       // K quarter (256)
  const int grp   = dir * 2 + bhalf;                // sync group (64 blocks)
  const int q4    = (lane >> 4) * 4;
  const int cl    = lane & 15;

  if (tid == 0) *ldsflag = 0;

  { // W slice: pack f32 -> bf16 MFMA-fragment order, straight into LDS (one-time)
    const float* Wsrc = dir ? Whhb : Whhf;
    for (int e = tid; e < 8192; e += 512) {
      int ln  = e & 63;
      int cg  = (e >> 6) & 3;
      int ks  = e >> 8;
      int col = cg * 16 + (ln & 15);
      int R   = (col & 3) * 1024 + jsl * 16 + (col >> 2);
      int kb  = ks * 32 + (ln >> 4) * 8;
      const float* src = Wsrc + (size_t)R * 1024 + kb;
      unsigned w0 = (unsigned)f2bf(src[0]) | ((unsigned)f2bf(src[1]) << 16);
      unsigned w1 = (unsigned)f2bf(src[2]) | ((unsigned)f2bf(src[3]) << 16);
      unsigned w2 = (unsigned)f2bf(src[4]) | ((unsigned)f2bf(src[5]) << 16);
      unsigned w3 = (unsigned)f2bf(src[6]) | ((unsigned)f2bf(src[7]) << 16);
      *((uint4*)(Wlds + (size_t)e * 8)) = make_uint4(w0, w1, w2, w3);
    }
  }

  // ---- pointwise ownership: waves 0..5 (tid<384): row r = p*24 + (tid>>4), j = tid&15 ----
  const int j    = tid & 15;
  const int rloc = tid >> 4;                        // 0..23 valid when tid<384
  const bool pw  = (tid < 384);
  const int jglob = jsl * 16 + j;
  float4 cf0, cf1, cf2, cf3;
  {
    const float4* cp = (const float4*)coef + ((dir * 64 + jsl) * 64 + j * 4);
    cf0 = cp[0]; cf1 = cp[1]; cf2 = cp[2]; cf3 = cp[3];
  }
  const float wlg = wlog[dir * 1024 + jglob];

  float creg[4];
  int   bgm[4];
  #pragma unroll
  for (int p = 0; p < 4; ++p) {
    int bg = bhalf * 96 + p * 24 + rloc;
    bgm[p]  = bg;
    creg[p] = pw ? c0[((size_t)dir * BATCH + bg) * HID + jglob] : 0.f;
  }

  // ---- GEMM-side addressing ----
  const int arow0 = bhalf * 96 + wm * 48 + 0 * 16 + cl;
  const int arow1 = arow0 + 16;
  const int arow2 = arow0 + 32;
  const int koff  = wk * 256 + (lane >> 4) * 8;                    // u16 units
  const u16* bWl  = Wlds + (size_t)wk * 16384 + lane * 8;          // LDS W stream

  float* pbase = part + ((size_t)(dir * 4 + (jsl & 3)) * BATCH) * T_STEPS;

  // flag barrier pointers: group base, own flag (jsl), poll target (lane)
  unsigned* gflags = bar + grp * 1024;              // 64 flags @ 16 u32 stride
  unsigned* myflag = gflags + jsl * 16;
  const unsigned* pollp = gflags + lane * 16;

  float lpv[4];
  int   lpo[4];

  int sp   = 0;      // ring source panel
  int invc = 0;      // inv countdown (CACHED only)

  __syncthreads();

  for (int s = 0; s < T_STEPS; ++s) {
    // ---- periodic L1+L2 invalidate (ring path) ----
    if constexpr (CACHED) {
      if (invc == 0) {
        if (wave == 0) {
          asm volatile("buffer_inv sc0 sc1" ::: "memory");
          asm volatile("s_waitcnt vmcnt(0)" ::: "memory");
        }
        __syncthreads();
      }
      if (++invc >= IV) invc = 0;
    }

    int dp = sp + 1; if (dp == PN) dp = 0;
    const u16* hsrc = hb + ((size_t)(dir * PN + sp)) * PANEL_ELEMS;
    u16*       hdst = hb + ((size_t)(dir * PN + dp)) * PANEL_ELEMS;
    sp = dp;
    const u16* ab0 = hsrc + (size_t)arow0 * HID + koff;
    const u16* ab1 = hsrc + (size_t)arow1 * HID + koff;
    const u16* ab2 = hsrc + (size_t)arow2 * HID + koff;

    f32x4 acc[3][4];
    #pragma unroll
    for (int mt = 0; mt < 3; ++mt)
      #pragma unroll
      for (int n = 0; n < 4; ++n)
        acc[mt][n] = (f32x4){0.f, 0.f, 0.f, 0.f};

    u32x4  aq[8][3];
    bf16x8 bv[2][4];

    // issue ALL 8 K-chunks of A up front (24 loads, one RTT exposure)
    if constexpr (CACHED) {
      ALD_C(0, 0)   ALD_C(1, 64)  ALD_C(2, 128) ALD_C(3, 192)
      ALD_C(4, 256) ALD_C(5, 320) ALD_C(6, 384) ALD_C(7, 448)
    } else {
      ALD_B(0, 0)   ALD_B(1, 64)  ALD_B(2, 128) ALD_B(3, 192)
      ALD_B(4, 256) ALD_B(5, 320) ALD_B(6, 384) ALD_B(7, 448)
    }

    BLDS(0, 0)
    BLDS(1, 1) WB(21) MM(0, 0)
    BLDS(0, 2) WB(18) MM(1, 1)
    BLDS(1, 3) WB(15) MM(2, 0)
    BLDS(0, 4) WB(12) MM(3, 1)
    BLDS(1, 5) WB(9)  MM(4, 0)
    BLDS(0, 6) WB(6)  MM(5, 1)
    BLDS(1, 7) WB(3)  MM(6, 0)
               WB(0)  MM(7, 1)

    const int t_x = dir ? (T_STEPS - 1 - s) : s;

    // ---- 4 quarter-row phases: masked dump -> sync -> gather+pointwise -> sync ----
    #pragma unroll
    for (int p = 0; p < 4; ++p) {
      if (wm == (p >> 1)) {
        const int plo = (p & 1) * 24;
        float* dst = DMP + wk * DMP_WK_STRIDE;
        #pragma unroll
        for (int mt = 0; mt < 3; ++mt)
          #pragma unroll
          for (int n = 0; n < 4; ++n)
            #pragma unroll
            for (int r = 0; r < 4; ++r) {
              int row = mt * 16 + q4 + r;
              if (row >= plo && row < plo + 24)
                dst[(row - plo) * 68 + n * 16 + cl] = acc[mt][n][r];
            }
      }
      __syncthreads();

      if (pw) {
        const int ga = rloc * 68 + (j >> 2) * 16 + (j & 3) * 4;
        f32x4 p0 = *(const f32x4*)(DMP + 0 * DMP_WK_STRIDE + ga);
        f32x4 p1 = *(const f32x4*)(DMP + 1 * DMP_WK_STRIDE + ga);
        f32x4 p2 = *(const f32x4*)(DMP + 2 * DMP_WK_STRIDE + ga);
        f32x4 p3 = *(const f32x4*)(DMP + 3 * DMP_WK_STRIDE + ga);
        f32x4 g4 = (p0 + p1) + (p2 + p3);          // (i,f,g,o)
        int bg = bgm[p];
        float2 xv = *(const float2*)(x + ((size_t)t_x * BATCH + bg) * 2);
        float pi = g4[0] + cf0.x * xv.x + cf0.y * xv.y + cf0.z;
        float pf = g4[1] + cf1.x * xv.x + cf1.y * xv.y + cf1.z;
        float pg = g4[2] + cf2.x * xv.x + cf2.y * xv.y + cf2.z;
        float po = g4[3] + cf3.x * xv.x + cf3.y * xv.y + cf3.z;
        float ig = sigm(pi), fg = sigm(pf), gv = tanh_f(pg), og = sigm(po);
        float c = fg * creg[p] + ig * gv;
        creg[p] = c;
        float h = og * tanh_f(c);
        u16* hp = hdst + (size_t)bg * HID + jglob;
        unsigned hv = (unsigned)f2bf(h);
        HST(hp, hv);
        float lp = h * wlg;
        lp += __shfl_xor(lp, 1);
        lp += __shfl_xor(lp, 2);
        lp += __shfl_xor(lp, 4);
        lp += __shfl_xor(lp, 8);
        lpv[p] = lp;
        lpo[p] = bg * T_STEPS + t_x;
      }
      __syncthreads();
    }

    // ---- drain own h stores (per-wave), then block-wide sync => all drained ----
    asm volatile("s_waitcnt vmcnt(0)" ::: "memory");
    __syncthreads();

    // ---- store/poll flag barrier (no RMWs); logit atomics AFTER the flag ----
    if (tid == 0) {
      unsigned nv = (unsigned)(s + 1);
      asm volatile("global_store_dword %0, %1, off sc0 sc1" :: "v"(myflag), "v"(nv) : "memory");
    }
    if (pw && j == 0) {
      atomicAdd(&pbase[lpo[0]], lpv[0]);
      atomicAdd(&pbase[lpo[1]], lpv[1]);
      atomicAdd(&pbase[lpo[2]], lpv[2]);
      atomicAdd(&pbase[lpo[3]], lpv[3]);
    }
    if (wave == 0) {
      const unsigned tgt = (unsigned)(s + 1);
      long guard = 0;
      for (;;) {
        unsigned fv;
        asm volatile("global_load_dword %0, %1, off sc0 sc1" : "=v"(fv) : "v"(pollp));
        asm volatile("s_waitcnt vmcnt(0)" ::: "memory");
        if (__all(fv >= tgt)) break;
        if (++guard > (1L << 20)) { if (lane == 0) *ldsflag = 1; break; }
        __builtin_amdgcn_s_sleep(1);
      }
    }
    __syncthreads();
    if (*ldsflag) return;   // sync failure: bail instead of hanging
  }
}

// ---------------- post: sum partials -> softmax -> cumsum -> Bezier -> curves + reg ----------------
__global__ void post_k(const float* __restrict__ part, const float* __restrict__ ctrl,
                       const float* __restrict__ ratw, float* __restrict__ out)
{
  __shared__ float sh[T_STEPS + 64];
  const int b = blockIdx.x;
  const int t = threadIdx.x;          // 320 threads
  float l = 0.f;
  #pragma unroll
  for (int p = 0; p < 8; ++p)
    l += part[((size_t)p * BATCH + b) * T_STEPS + t];
  sh[t] = l;
  __syncthreads();
  if (t < 64) {
    float mm = sh[t];
    for (int i = t + 64; i < T_STEPS; i += 64) mm = fmaxf(mm, sh[i]);
    #pragma unroll
    for (int o = 32; o; o >>= 1) mm = fmaxf(mm, __shfl_xor(mm, o));
    if (t == 0) sh[T_STEPS] = mm;
  }
  __syncthreads();
  const float m = sh[T_STEPS];
  float e = __expf(l - m);
  __syncthreads();
  sh[t] = e;
  __syncthreads();
  for (int off = 1; off < T_STEPS; off <<= 1) {
    float v = (t >= off) ? sh[t - off] : 0.f;
    __syncthreads();
    sh[t] += v;
    __syncthreads();
  }
  const float total = sh[T_STEPS - 1];
  const float ts = sh[t] / total;

  float px[8], py[8], rr[8];
  #pragma unroll
  for (int n = 0; n < 8; ++n) {
    px[n] = ctrl[b * 16 + 2 * n];
    py[n] = ctrl[b * 16 + 2 * n + 1];
    rr[n] = ratw[b * 8 + n];
  }
  const float C[8] = {1.f, 7.f, 21.f, 35.f, 35.f, 21.f, 7.f, 1.f};
  float tp[8], up[8];
  tp[0] = 1.f; up[0] = 1.f;
  const float u = 1.f - ts;
  #pragma unroll
  for (int n = 1; n < 8; ++n) { tp[n] = tp[n - 1] * ts; up[n] = up[n - 1] * u; }
  float den = 0.f, nx = 0.f, ny = 0.f;
  #pragma unroll
  for (int n = 0; n < 8; ++n) {
    float w = C[n] * tp[n] * up[7 - n] * rr[n];
    den += w; nx += w * px[n]; ny += w * py[n];
  }
  out[(b * T_STEPS + t) * 2 + 0] = nx / den;
  out[(b * T_STEPS + t) * 2 + 1] = ny / den;

  if (b == 0) {   // regularizer scalar
    __syncthreads();
    if (t < BATCH) {
      float s2 = 0.f;
      #pragma unroll
      for (int n = 0; n < 7; ++n) {
        float dx = ctrl[t * 16 + 2 * n + 2] - ctrl[t * 16 + 2 * n + 0];
        float dy = ctrl[t * 16 + 2 * n + 3] - ctrl[t * 16 + 2 * n + 1];
        s2 += dx * dx + dy * dy;
      }
      sh[t] = s2;
    }
    __syncthreads();
    if (t == 0) {
      float tot = 0.f;
      for (int i = 0; i < BATCH; ++i) tot += sh[i];
      out[BATCH * T_STEPS * 2] = tot / (float)(BATCH * 7);
    }
  }
}

extern "C" void kernel_launch(void* const* d_in, const int* in_sizes, int n_in,
                              void* d_out, int out_size, void* d_ws, size_t ws_size,
                              hipStream_t stream)
{
  const float* x    = (const float*)d_in[0];
  const float* ctrl = (const float*)d_in[1];
  const float* ratw = (const float*)d_in[2];
  const float* Whf  = (const float*)d_in[3];
  const float* bhf  = (const float*)d_in[4];
  const float* Whb  = (const float*)d_in[5];
  const float* bhb  = (const float*)d_in[6];
  const float* Wcf  = (const float*)d_in[7];
  const float* bcf  = (const float*)d_in[8];
  const float* Wcb  = (const float*)d_in[9];
  const float* bcb  = (const float*)d_in[10];
  const float* Wihf = (const float*)d_in[11];
  const float* Whhf = (const float*)d_in[12];
  const float* bihf = (const float*)d_in[13];
  const float* bhhf = (const float*)d_in[14];
  const float* Wihb = (const float*)d_in[15];
  const float* Whhb = (const float*)d_in[16];
  const float* bihb = (const float*)d_in[17];
  const float* bhhb = (const float*)d_in[18];
  const float* Wlog = (const float*)d_in[19];
  float* out = (float*)d_out;
  char*  ws  = (char*)d_ws;
  if (ws_size < (size_t)WS_NEED) return;

  // ring sizing from available workspace
  size_t availB = (ws_size > (size_t)OFF_HT) ? (ws_size - (size_t)OFF_HT) : 0;
  long Pl = (long)(availB / (size_t)P_COST);
  int P = (int)(Pl > 322 ? 322 : Pl);
  const bool cached = (P >= 4);

  unsigned* bar    = (unsigned*)(ws + OFF_BAR);
  float*    part   = (float*)(ws + OFF_PART);
  float*    c0     = (float*)(ws + OFF_C0);
  u16*      hsmall = (u16*)(ws + OFF_H);
  u16*      hring  = (u16*)(ws + OFF_HT);
  float*    coef   = (float*)(ws + OFF_COEF);

  u16*   hb      = cached ? hring : hsmall;
  int    PN      = cached ? P : 2;
  int    IV      = (cached && P < 322) ? (P - 2) : (1 << 30);
  size_t hstride = (size_t)PN * PANEL_ELEMS;

  hipMemsetAsync(ws, 0, MEMSET_BYTES, stream);   // flags + partial logits
  coef_k<<<32, 256, 0, stream>>>(Wihf, bihf, bhhf, Wihb, bihb, bhhb, coef);
  init_k<<<dim3(768, 4), 256, 0, stream>>>(ctrl, ratw, Whf, bhf, Whb, bhb,
                                           Wcf, bcf, Wcb, bcb, hb, c0, hstride);
  if (cached) {
    hipFuncSetAttribute((const void*)lstm_persist<1>,
                        hipFuncAttributeMaxDynamicSharedMemorySize, DYN_LDS);
    lstm_persist<1><<<NBLK, 512, DYN_LDS, stream>>>(x, Wlog, part, c0, hb, Whhf, Whhb, coef, bar, PN, IV);
  } else {
    hipFuncSetAttribute((const void*)lstm_persist<0>,
                        hipFuncAttributeMaxDynamicSharedMemorySize, DYN_LDS);
    lstm_persist<0><<<NBLK, 512, DYN_LDS, stream>>>(x, Wlog, part, c0, hb, Whhf, Whhb, coef, bar, PN, IV);
  }
  post_k<<<BATCH, T_STEPS, 0, stream>>>(part, ctrl, ratw, out);
}